// Round 11
// baseline (138.673 us; speedup 1.0000x reference)
//
#include <hip/hip_runtime.h>
#include <cstdint>
#include <cstddef>

// Dims (fixed by the reference)
#define R_   16
#define NH_  8
#define D_   32
#define C_   256
#define B_   16
#define XY_  1024      // 32*32
#define RH_  128       // R_*NH_
#define KD_  4096      // R_*NH_*D_
#define NPOS (B_*XY_)  // 16384 positions
#define NT   64        // positions per block (lane = position)

#define LD4(p) (*reinterpret_cast<const float4*>(p))

// ---------------------------------------------------------------------------
// Precompute, 2x parallel (256 blocks): bid = rh*2 + half. (unchanged)
//   half 0: k[d] = Wk[r,h*D+d,:]·rims[r,:]+bk  ->  WLt[c][rh], c0[rh]
//   half 1: v[d] = Wv[...]·rims+bv             ->  Uo[rh][c]
// ---------------------------------------------------------------------------
__global__ __launch_bounds__(256)
void rims_precompute(const float* __restrict__ rims,
                     const float* __restrict__ Wk,
                     const float* __restrict__ bk,
                     const float* __restrict__ Wv,
                     const float* __restrict__ bv,
                     const float* __restrict__ Wq,
                     const float* __restrict__ bq,
                     const float* __restrict__ Wm,
                     float* __restrict__ WLt,
                     float* __restrict__ Uo,
                     float* __restrict__ c0o)
{
    const int bid  = blockIdx.x;       // 0..255
    const int rh   = bid >> 1;         // 0..127
    const int half = bid & 1;          // 0: k/WLt, 1: v/Uo
    const int r    = rh >> 3;
    const int h    = rh & 7;
    const int tid  = threadIdx.x;

    __shared__ float kv[D_];

    {
        const int d    = tid >> 3;     // 0..31
        const int part = tid & 7;      // 0..7
        const float* Wsrc = (half ? Wv : Wk)
                          + ((size_t)r * 256 + h * D_ + d) * C_ + part * 32;
        const float* rr   = rims + r * C_ + part * 32;
        float a0 = 0.f, a1 = 0.f, a2 = 0.f, a3 = 0.f;
        #pragma unroll
        for (int j = 0; j < 8; ++j) {
            const float4 wv4 = LD4(Wsrc + j * 4);
            const float4 xv4 = LD4(rr + j * 4);
            a0 = fmaf(wv4.x, xv4.x, a0); a1 = fmaf(wv4.y, xv4.y, a1);
            a2 = fmaf(wv4.z, xv4.z, a2); a3 = fmaf(wv4.w, xv4.w, a3);
        }
        float acc = (a0 + a1) + (a2 + a3);
        acc += __shfl_xor(acc, 1);
        acc += __shfl_xor(acc, 2);
        acc += __shfl_xor(acc, 4);
        if (part == 0)
            kv[d] = acc + (half ? bv : bk)[r * 256 + h * D_ + d];
    }
    __syncthreads();

    const int c = tid;                 // 0..255
    if (half == 0) {
        float wl = 0.f;
        const float* wqp = Wq + (size_t)rh * D_ * C_ + c;
        #pragma unroll
        for (int d = 0; d < D_; ++d)
            wl = fmaf(kv[d], wqp[(size_t)d * C_], wl);
        WLt[c * RH_ + rh] = wl;        // [c][rh]

        if (tid < D_) {
            float s = kv[tid] * bq[rh * D_ + tid];
            s += __shfl_xor(s, 1);  s += __shfl_xor(s, 2);  s += __shfl_xor(s, 4);
            s += __shfl_xor(s, 8);  s += __shfl_xor(s, 16);
            if (tid == 0) c0o[rh] = s;
        }
    } else {
        float uu = 0.f;
        const float* wmp = Wm + (size_t)c * KD_ + rh * D_;
        #pragma unroll
        for (int d4 = 0; d4 < D_; d4 += 4) {
            const float4 m4 = LD4(wmp + d4);
            uu = fmaf(kv[d4 + 0], m4.x, uu);
            uu = fmaf(kv[d4 + 1], m4.y, uu);
            uu = fmaf(kv[d4 + 2], m4.z, uu);
            uu = fmaf(kv[d4 + 3], m4.w, uu);
        }
        Uo[rh * C_ + c] = uu;          // [rh][c]
    }
}

// ---------------------------------------------------------------------------
// Fused main: 256 blocks x 1024 threads (16 waves). lane = position.
// KEY CHANGE vs R8: wave id w = tid>>6 WITHOUT readfirstlane -> weight
// addresses are divergent to the compiler -> weights load via VMEM
// (global_load_dwordx4, same-address lanes coalesce+broadcast), which is
// IN-ORDER and vmcnt-COUNTED -> compiler software-pipelines them. No SMEM
// in the hot loops => no lgkmcnt(0) full drains; lgkm carries only GEMM2's
// attn ds_reads (fine-grained).
//   GEMM1 2-way split-K: wave (kh = w&1, mg = w>>1): 16 rh rows over 128 c.
//     z read per-lane in-loop (counted VMEM), 16 FMA per z load.
//     Partials -> P0 (kh=0) / P1 (kh=1).
//   softmax (waves 0..7): vals = P0+P1+c0, in-register, attn -> P0.
//   GEMM2: wave w -> 16 c rows, K=128: 1 ds_read + 4 VMEM float4 + 16 FMA.
// LDS = 64 KB. All LDS lane-stride-1 (conflict-free).
// ---------------------------------------------------------------------------
__global__ __launch_bounds__(1024, 4)
void rims_main(const float* __restrict__ z,
               const float* __restrict__ WLt,
               const float* __restrict__ Uo,
               const float* __restrict__ c0v,
               const float* __restrict__ bm,
               float* __restrict__ out)
{
    __shared__ __align__(16) float P0[RH_ * NT];   // 32 KB
    __shared__ __align__(16) float P1[RH_ * NT];   // 32 KB

    const int tid  = threadIdx.x;
    const int lane = tid & 63;
    const int w    = tid >> 6;         // divergent on purpose (VMEM weights)
    const int kh   = w & 1;            // K-half
    const int rh0  = (w >> 1) << 4;    // 0..112
    const int b    = blockIdx.x >> 4;
    const int xy0  = (blockIdx.x & 15) * NT;

    // ---- GEMM1: 16 rh rows x 128 c per wave ----
    {
        const float* zg = z + ((size_t)b * C_ + kh * 128) * XY_ + xy0 + lane;
        const float* wp = WLt + (size_t)(kh * 128) * RH_ + rh0;

        float acc[16];
        #pragma unroll
        for (int m = 0; m < 16; ++m) acc[m] = 0.f;

        #pragma unroll 2
        for (int j = 0; j < 128; ++j) {
            const float  zv = zg[(size_t)j * XY_];
            const float4 w0 = LD4(wp + (size_t)j * RH_ + 0);
            const float4 w1 = LD4(wp + (size_t)j * RH_ + 4);
            const float4 w2 = LD4(wp + (size_t)j * RH_ + 8);
            const float4 w3 = LD4(wp + (size_t)j * RH_ + 12);
            acc[ 0] = fmaf(w0.x, zv, acc[ 0]);
            acc[ 1] = fmaf(w0.y, zv, acc[ 1]);
            acc[ 2] = fmaf(w0.z, zv, acc[ 2]);
            acc[ 3] = fmaf(w0.w, zv, acc[ 3]);
            acc[ 4] = fmaf(w1.x, zv, acc[ 4]);
            acc[ 5] = fmaf(w1.y, zv, acc[ 5]);
            acc[ 6] = fmaf(w1.z, zv, acc[ 6]);
            acc[ 7] = fmaf(w1.w, zv, acc[ 7]);
            acc[ 8] = fmaf(w2.x, zv, acc[ 8]);
            acc[ 9] = fmaf(w2.y, zv, acc[ 9]);
            acc[10] = fmaf(w2.z, zv, acc[10]);
            acc[11] = fmaf(w2.w, zv, acc[11]);
            acc[12] = fmaf(w3.x, zv, acc[12]);
            acc[13] = fmaf(w3.y, zv, acc[13]);
            acc[14] = fmaf(w3.z, zv, acc[14]);
            acc[15] = fmaf(w3.w, zv, acc[15]);
        }

        float* pp = (kh ? P1 : P0) + rh0 * NT + lane;
        #pragma unroll
        for (int m = 0; m < 16; ++m)
            pp[m * NT] = acc[m];
    }
    __syncthreads();

    // ---- softmax over r per (h,p); folds split-K reduce + c0. waves 0..7 ----
    if (tid < 512) {
        const int h = tid >> 6;        // 0..7
        float v[R_];
        float mx = -1e30f;
        #pragma unroll
        for (int r = 0; r < R_; ++r) {
            const int row = r * NH_ + h;
            const int idx = row * NT + lane;
            v[r] = (P0[idx] + P1[idx]) + c0v[row];
            mx = fmaxf(mx, v[r]);
        }
        float s = 0.f;
        #pragma unroll
        for (int r = 0; r < R_; ++r) { v[r] = __expf(v[r] - mx); s += v[r]; }
        const float inv = 1.f / s;
        #pragma unroll
        for (int r = 0; r < R_; ++r)
            P0[(r * NH_ + h) * NT + lane] = v[r] * inv;
    }
    __syncthreads();

    // ---- GEMM2: wave w -> c rows [16w, 16w+16), K = 128 ----
    {
        const int c0 = w << 4;
        const float* up = Uo + c0;     // divergent base -> VMEM float4 weights

        float acc[16];
        #pragma unroll
        for (int j = 0; j < 16; ++j) acc[j] = 0.f;

        #pragma unroll 2
        for (int rh = 0; rh < RH_; ++rh) {
            const float  av = P0[rh * NT + lane];
            const float4 u0 = LD4(up + (size_t)rh * C_ + 0);
            const float4 u1 = LD4(up + (size_t)rh * C_ + 4);
            const float4 u2 = LD4(up + (size_t)rh * C_ + 8);
            const float4 u3 = LD4(up + (size_t)rh * C_ + 12);
            acc[ 0] = fmaf(u0.x, av, acc[ 0]);
            acc[ 1] = fmaf(u0.y, av, acc[ 1]);
            acc[ 2] = fmaf(u0.z, av, acc[ 2]);
            acc[ 3] = fmaf(u0.w, av, acc[ 3]);
            acc[ 4] = fmaf(u1.x, av, acc[ 4]);
            acc[ 5] = fmaf(u1.y, av, acc[ 5]);
            acc[ 6] = fmaf(u1.z, av, acc[ 6]);
            acc[ 7] = fmaf(u1.w, av, acc[ 7]);
            acc[ 8] = fmaf(u2.x, av, acc[ 8]);
            acc[ 9] = fmaf(u2.y, av, acc[ 9]);
            acc[10] = fmaf(u2.z, av, acc[10]);
            acc[11] = fmaf(u2.w, av, acc[11]);
            acc[12] = fmaf(u3.x, av, acc[12]);
            acc[13] = fmaf(u3.y, av, acc[13]);
            acc[14] = fmaf(u3.z, av, acc[14]);
            acc[15] = fmaf(u3.w, av, acc[15]);
        }

        float* ob = out + ((size_t)b * C_ + c0) * XY_ + xy0 + lane;
        #pragma unroll
        for (int j = 0; j < 16; ++j)
            ob[(size_t)j * XY_] = acc[j] + bm[c0 + j];
    }
}

// ---------------------------------------------------------------------------
extern "C" void kernel_launch(void* const* d_in, const int* in_sizes, int n_in,
                              void* d_out, int out_size, void* d_ws, size_t ws_size,
                              hipStream_t stream)
{
    const float* z    = (const float*)d_in[0];
    const float* rims = (const float*)d_in[1];
    const float* Wk   = (const float*)d_in[2];
    const float* bk   = (const float*)d_in[3];
    const float* Wv   = (const float*)d_in[4];
    const float* bv   = (const float*)d_in[5];
    const float* Wq   = (const float*)d_in[6];
    const float* bq   = (const float*)d_in[7];
    const float* Wm   = (const float*)d_in[8];
    const float* bm   = (const float*)d_in[9];
    float* out = (float*)d_out;

    // ws layout: WLt (C_*RH_) | Uo (RH_*C_) | c0 (RH_)  -> ~257 KB
    float* WLt = (float*)d_ws;
    float* Uo  = WLt + C_ * RH_;
    float* c0o = Uo + RH_ * C_;

    rims_precompute<<<2 * RH_, 256, 0, stream>>>(rims, Wk, bk, Wv, bv, Wq, bq, Wm,
                                                 WLt, Uo, c0o);
    rims_main<<<(B_ * XY_) / NT, 1024, 0, stream>>>(z, WLt, Uo, c0o, bm, out);
}

// Round 12
// 57.530 us; speedup vs baseline: 2.4104x; 2.4104x over previous
//
#include <hip/hip_runtime.h>
#include <cstdint>
#include <cstddef>

// Dims (fixed by the reference)
#define R_   16
#define NH_  8
#define D_   32
#define C_   256
#define B_   16
#define XY_  1024      // 32*32
#define RH_  128       // R_*NH_
#define KD_  4096      // R_*NH_*D_
#define NT   64        // positions per block (lane = position)

#define LD4(p) (*reinterpret_cast<const float4*>(p))

// ---------------------------------------------------------------------------
// Precompute, 2x parallel (256 blocks): bid = rh*2 + half. (unchanged)
//   half 0: k[d] = Wk[r,h*D+d,:]·rims[r,:]+bk  ->  WLt[c][rh], c0[rh]
//   half 1: v[d] = Wv[...]·rims+bv             ->  Uo[rh][c]
// ---------------------------------------------------------------------------
__global__ __launch_bounds__(256)
void rims_precompute(const float* __restrict__ rims,
                     const float* __restrict__ Wk,
                     const float* __restrict__ bk,
                     const float* __restrict__ Wv,
                     const float* __restrict__ bv,
                     const float* __restrict__ Wq,
                     const float* __restrict__ bq,
                     const float* __restrict__ Wm,
                     float* __restrict__ WLt,
                     float* __restrict__ Uo,
                     float* __restrict__ c0o)
{
    const int bid  = blockIdx.x;       // 0..255
    const int rh   = bid >> 1;         // 0..127
    const int half = bid & 1;          // 0: k/WLt, 1: v/Uo
    const int r    = rh >> 3;
    const int h    = rh & 7;
    const int tid  = threadIdx.x;

    __shared__ float kv[D_];

    {
        const int d    = tid >> 3;     // 0..31
        const int part = tid & 7;      // 0..7
        const float* Wsrc = (half ? Wv : Wk)
                          + ((size_t)r * 256 + h * D_ + d) * C_ + part * 32;
        const float* rr   = rims + r * C_ + part * 32;
        float a0 = 0.f, a1 = 0.f, a2 = 0.f, a3 = 0.f;
        #pragma unroll
        for (int j = 0; j < 8; ++j) {
            const float4 wv4 = LD4(Wsrc + j * 4);
            const float4 xv4 = LD4(rr + j * 4);
            a0 = fmaf(wv4.x, xv4.x, a0); a1 = fmaf(wv4.y, xv4.y, a1);
            a2 = fmaf(wv4.z, xv4.z, a2); a3 = fmaf(wv4.w, xv4.w, a3);
        }
        float acc = (a0 + a1) + (a2 + a3);
        acc += __shfl_xor(acc, 1);
        acc += __shfl_xor(acc, 2);
        acc += __shfl_xor(acc, 4);
        if (part == 0)
            kv[d] = acc + (half ? bv : bk)[r * 256 + h * D_ + d];
    }
    __syncthreads();

    const int c = tid;                 // 0..255
    if (half == 0) {
        float wl = 0.f;
        const float* wqp = Wq + (size_t)rh * D_ * C_ + c;
        #pragma unroll
        for (int d = 0; d < D_; ++d)
            wl = fmaf(kv[d], wqp[(size_t)d * C_], wl);
        WLt[c * RH_ + rh] = wl;        // [c][rh]

        if (tid < D_) {
            float s = kv[tid] * bq[rh * D_ + tid];
            s += __shfl_xor(s, 1);  s += __shfl_xor(s, 2);  s += __shfl_xor(s, 4);
            s += __shfl_xor(s, 8);  s += __shfl_xor(s, 16);
            if (tid == 0) c0o[rh] = s;
        }
    } else {
        float uu = 0.f;
        const float* wmp = Wm + (size_t)c * KD_ + rh * D_;
        #pragma unroll
        for (int d4 = 0; d4 < D_; d4 += 4) {
            const float4 m4 = LD4(wmp + d4);
            uu = fmaf(kv[d4 + 0], m4.x, uu);
            uu = fmaf(kv[d4 + 1], m4.y, uu);
            uu = fmaf(kv[d4 + 2], m4.z, uu);
            uu = fmaf(kv[d4 + 3], m4.w, uu);
        }
        Uo[rh * C_ + c] = uu;          // [rh][c]
    }
}

// ---------------------------------------------------------------------------
// Fused main: 512 blocks x 512 threads (8 waves) -> 2 INDEPENDENT blocks/CU.
// Same per-wave shapes as R8 (the 46.9us best): lane = position, weights via
// readfirstlane-pinned SMEM (s_load), z per-lane in-order VMEM.
//   GEMM1 2-way split-K: wave (kh=w&1, mg=w>>1): 32 rh rows over 128 c.
//     Per k-step: 1 z VMEM + 128 B uniform SMEM + 32 FMA-instr.
//     Partials -> P0 (kh=0) / P1 (kh=1).
//   softmax (all 8 waves, h=w): vals = P0+P1+c0 in registers, attn -> P0.
//   GEMM2: wave w -> 32 c rows, K=128: 1 ds_read + 128 B SMEM + 32 FMA/step.
// LDS = 64 KB -> exactly 2 blocks/CU; when one block drains SMEM or sits at
// a barrier, the other block's waves keep the SIMDs fed.
// ---------------------------------------------------------------------------
__global__ __launch_bounds__(512, 2)
void rims_main(const float* __restrict__ z,
               const float* __restrict__ WLt,
               const float* __restrict__ Uo,
               const float* __restrict__ c0v,
               const float* __restrict__ bm,
               float* __restrict__ out)
{
    __shared__ __align__(16) float P0[RH_ * NT];   // 32 KB
    __shared__ __align__(16) float P1[RH_ * NT];   // 32 KB

    const int tid  = threadIdx.x;
    const int lane = tid & 63;
    const int w    = __builtin_amdgcn_readfirstlane(tid >> 6);  // 0..7 uniform
    const int kh   = w & 1;            // K-half
    const int rh0  = (w >> 1) << 5;    // 0,32,64,96
    const int b    = blockIdx.x >> 4;
    const int xy0  = (blockIdx.x & 15) * NT;

    // ---- GEMM1: 32 rh rows x 128 c per wave ----
    {
        const float* zg = z + ((size_t)b * C_ + kh * 128) * XY_ + xy0 + lane;
        const float* wp = WLt + (size_t)(kh * 128) * RH_ + rh0;   // uniform

        float acc[32];
        #pragma unroll
        for (int m = 0; m < 32; ++m) acc[m] = 0.f;

        #pragma unroll 2
        for (int j = 0; j < 128; ++j) {
            const float zv = zg[(size_t)j * XY_];
            const float* wr = wp + (size_t)j * RH_;
            #pragma unroll
            for (int m = 0; m < 32; ++m)
                acc[m] = fmaf(wr[m], zv, acc[m]);
        }

        float* pp = (kh ? P1 : P0) + rh0 * NT + lane;
        #pragma unroll
        for (int m = 0; m < 32; ++m)
            pp[m * NT] = acc[m];
    }
    __syncthreads();

    // ---- softmax over r per (h,p); folds split-K reduce + c0 ----
    {
        const int h = w;               // 0..7
        float v[R_];
        float mx = -1e30f;
        #pragma unroll
        for (int r = 0; r < R_; ++r) {
            const int row = r * NH_ + h;
            const int idx = row * NT + lane;
            v[r] = (P0[idx] + P1[idx]) + c0v[row];
            mx = fmaxf(mx, v[r]);
        }
        float s = 0.f;
        #pragma unroll
        for (int r = 0; r < R_; ++r) { v[r] = __expf(v[r] - mx); s += v[r]; }
        const float inv = 1.f / s;
        #pragma unroll
        for (int r = 0; r < R_; ++r)
            P0[(r * NH_ + h) * NT + lane] = v[r] * inv;
    }
    __syncthreads();

    // ---- GEMM2: wave w -> c rows [32w, 32w+32), K = 128 ----
    {
        const int c0 = w << 5;
        const float* up = Uo + c0;     // uniform; row stride C_

        float acc[32];
        #pragma unroll
        for (int m = 0; m < 32; ++m) acc[m] = 0.f;

        #pragma unroll 2
        for (int rh = 0; rh < RH_; ++rh) {
            const float av = P0[rh * NT + lane];
            const float* ur = up + (size_t)rh * C_;
            #pragma unroll
            for (int m = 0; m < 32; ++m)
                acc[m] = fmaf(ur[m], av, acc[m]);
        }

        float* ob = out + ((size_t)b * C_ + c0) * XY_ + xy0 + lane;
        #pragma unroll
        for (int m = 0; m < 32; ++m)
            ob[(size_t)m * XY_] = acc[m] + bm[c0 + m];
    }
}

// ---------------------------------------------------------------------------
extern "C" void kernel_launch(void* const* d_in, const int* in_sizes, int n_in,
                              void* d_out, int out_size, void* d_ws, size_t ws_size,
                              hipStream_t stream)
{
    const float* z    = (const float*)d_in[0];
    const float* rims = (const float*)d_in[1];
    const float* Wk   = (const float*)d_in[2];
    const float* bk   = (const float*)d_in[3];
    const float* Wv   = (const float*)d_in[4];
    const float* bv   = (const float*)d_in[5];
    const float* Wq   = (const float*)d_in[6];
    const float* bq   = (const float*)d_in[7];
    const float* Wm   = (const float*)d_in[8];
    const float* bm   = (const float*)d_in[9];
    float* out = (float*)d_out;

    // ws layout: WLt (C_*RH_) | Uo (RH_*C_) | c0 (RH_)  -> ~257 KB
    float* WLt = (float*)d_ws;
    float* Uo  = WLt + C_ * RH_;
    float* c0o = Uo + RH_ * C_;

    rims_precompute<<<2 * RH_, 256, 0, stream>>>(rims, Wk, bk, Wv, bv, Wq, bq, Wm,
                                                 WLt, Uo, c0o);
    rims_main<<<(B_ * XY_) / NT, 512, 0, stream>>>(z, WLt, Uo, c0o, bm, out);
}

// Round 13
// 34.293 us; speedup vs baseline: 4.0438x; 1.6776x over previous
//
#include <hip/hip_runtime.h>
#include <cstdint>
#include <cstddef>

// Dims (fixed by the reference)
#define R_   16
#define NH_  8
#define D_   32
#define C_   256
#define B_   16
#define XY_  1024      // 32*32
#define RH_  128       // R_*NH_
#define KD_  4096      // R_*NH_*D_
#define NT   64        // positions per block
#define LST  66        // Ls padded stride (floats)

#define LD4(p) (*reinterpret_cast<const float4*>(p))

using short8 = __attribute__((ext_vector_type(8))) short;   // 8 bf16 (4 VGPR)
using f32x16 = __attribute__((ext_vector_type(16))) float;  // MFMA 32x32 acc

__device__ __forceinline__ short bf16rn(float x) {
    unsigned u = __float_as_uint(x);
    u = (u + 0x7FFFu + ((u >> 16) & 1u)) >> 16;
    return (short)u;
}
__device__ __forceinline__ float bf16tof(short h) {
    return __uint_as_float(((unsigned)(unsigned short)h) << 16);
}

// ---------------------------------------------------------------------------
// Precompute (unchanged): WLt[c][rh], Uo[rh][c], c0[rh]
// ---------------------------------------------------------------------------
__global__ __launch_bounds__(256)
void rims_precompute(const float* __restrict__ rims,
                     const float* __restrict__ Wk,
                     const float* __restrict__ bk,
                     const float* __restrict__ Wv,
                     const float* __restrict__ bv,
                     const float* __restrict__ Wq,
                     const float* __restrict__ bq,
                     const float* __restrict__ Wm,
                     float* __restrict__ WLt,
                     float* __restrict__ Uo,
                     float* __restrict__ c0o)
{
    const int bid  = blockIdx.x;       // 0..255
    const int rh   = bid >> 1;
    const int half = bid & 1;
    const int r    = rh >> 3;
    const int h    = rh & 7;
    const int tid  = threadIdx.x;

    __shared__ float kv[D_];

    {
        const int d    = tid >> 3;
        const int part = tid & 7;
        const float* Wsrc = (half ? Wv : Wk)
                          + ((size_t)r * 256 + h * D_ + d) * C_ + part * 32;
        const float* rr   = rims + r * C_ + part * 32;
        float a0 = 0.f, a1 = 0.f, a2 = 0.f, a3 = 0.f;
        #pragma unroll
        for (int j = 0; j < 8; ++j) {
            const float4 wv4 = LD4(Wsrc + j * 4);
            const float4 xv4 = LD4(rr + j * 4);
            a0 = fmaf(wv4.x, xv4.x, a0); a1 = fmaf(wv4.y, xv4.y, a1);
            a2 = fmaf(wv4.z, xv4.z, a2); a3 = fmaf(wv4.w, xv4.w, a3);
        }
        float acc = (a0 + a1) + (a2 + a3);
        acc += __shfl_xor(acc, 1);
        acc += __shfl_xor(acc, 2);
        acc += __shfl_xor(acc, 4);
        if (part == 0)
            kv[d] = acc + (half ? bv : bk)[r * 256 + h * D_ + d];
    }
    __syncthreads();

    const int c = tid;
    if (half == 0) {
        float wl = 0.f;
        const float* wqp = Wq + (size_t)rh * D_ * C_ + c;
        #pragma unroll
        for (int d = 0; d < D_; ++d)
            wl = fmaf(kv[d], wqp[(size_t)d * C_], wl);
        WLt[c * RH_ + rh] = wl;

        if (tid < D_) {
            float s = kv[tid] * bq[rh * D_ + tid];
            s += __shfl_xor(s, 1);  s += __shfl_xor(s, 2);  s += __shfl_xor(s, 4);
            s += __shfl_xor(s, 8);  s += __shfl_xor(s, 16);
            if (tid == 0) c0o[rh] = s;
        }
    } else {
        float uu = 0.f;
        const float* wmp = Wm + (size_t)c * KD_ + rh * D_;
        #pragma unroll
        for (int d4 = 0; d4 < D_; d4 += 4) {
            const float4 m4 = LD4(wmp + d4);
            uu = fmaf(kv[d4 + 0], m4.x, uu);
            uu = fmaf(kv[d4 + 1], m4.y, uu);
            uu = fmaf(kv[d4 + 2], m4.z, uu);
            uu = fmaf(kv[d4 + 3], m4.w, uu);
        }
        Uo[rh * C_ + c] = uu;
    }
}

// ---------------------------------------------------------------------------
// Pack weights into per-lane MFMA fragment order (hi/lo bf16 split).
// Fragment convention (32x32x16, shared by A and B): lane l: non-K index
// = l&31, K-slot e=0..7 -> k = 8*(l>>5)+e (any shared bijection is valid).
//   WLf tile (kt,mt): A[m=rh][k=c]: rh=mt*32+(l&31), c=kt*16+8g+e
//   Uf  tile (kt,mt): A[m=c][k=rh]: c=mt*32+(l&31), rh=kt*16+8g+e
// bm folded into U: sum_rh attn = NH_ = 8  ->  U' = Uo + bm/8.
// ---------------------------------------------------------------------------
__global__ __launch_bounds__(64)
void rims_pack(const float* __restrict__ WLt, const float* __restrict__ Uo,
               const float* __restrict__ bm,
               short* __restrict__ WLf_hi, short* __restrict__ WLf_lo,
               short* __restrict__ Uf_hi,  short* __restrict__ Uf_lo)
{
    const int bid = blockIdx.x;        // 0..127
    const int l   = threadIdx.x;       // 0..63
    const int g   = l >> 5;
    const int n31 = l & 31;

    float x[8];
    short8 hi, lo;

    if (bid < 64) {                    // WLf tiles: kt(16) x mt(4)
        const int kt = bid >> 2, mt = bid & 3;
        #pragma unroll
        for (int e = 0; e < 8; ++e)
            x[e] = WLt[(size_t)(kt * 16 + 8 * g + e) * RH_ + mt * 32 + n31];
        #pragma unroll
        for (int e = 0; e < 8; ++e) {
            const short h = bf16rn(x[e]);
            hi[e] = h;
            lo[e] = bf16rn(x[e] - bf16tof(h));
        }
        *reinterpret_cast<short8*>(WLf_hi + ((size_t)bid * 64 + l) * 8) = hi;
        *reinterpret_cast<short8*>(WLf_lo + ((size_t)bid * 64 + l) * 8) = lo;
    } else {                           // Uf tiles: kt(8) x mt(8)
        const int idx = bid - 64;
        const int kt = idx >> 3, mt = idx & 7;
        const int c = mt * 32 + n31;
        #pragma unroll
        for (int e = 0; e < 8; ++e)
            x[e] = Uo[(size_t)(kt * 16 + 8 * g + e) * C_ + c] + 0.125f * bm[c];
        #pragma unroll
        for (int e = 0; e < 8; ++e) {
            const short h = bf16rn(x[e]);
            hi[e] = h;
            lo[e] = bf16rn(x[e] - bf16tof(h));
        }
        *reinterpret_cast<short8*>(Uf_hi + ((size_t)idx * 64 + l) * 8) = hi;
        *reinterpret_cast<short8*>(Uf_lo + ((size_t)idx * 64 + l) * 8) = lo;
    }
}

// ---------------------------------------------------------------------------
// MFMA main: 256 blocks x 512 thr (8 waves), 64 positions per block.
// Exact bf16-split (hi+lo, 3 products) on v_mfma_f32_32x32x16_bf16.
//   Phase 0: build GEMM1 B-frags (z) global->regs->cvt->Bf LDS (1KB frags)
//   Phase 1: GEMM1  L[rh][pos] : wave (mt=w&3, nt=w>>2), 16 kt, 3 MFMA/kt
//   Phase 2: softmax over r (+c0) in registers, attn -> Ls
//   Phase 3: build GEMM2 B-frags (attn) from Ls -> Bf (reused)
//   Phase 4: GEMM2  out[c][pos]: wave (mp=w>>1, nt=w&1), 2 mtiles, 8 kt
// A-fragments stream from pre-packed global (coalesced b128, L2-hot).
// LDS = 64KB Bf + 33.8KB Ls = 98KB -> 1 block/CU.
// ---------------------------------------------------------------------------
__global__ __launch_bounds__(512, 2)
void rims_mfma(const float* __restrict__ z,
               const short* __restrict__ WLf_hi, const short* __restrict__ WLf_lo,
               const short* __restrict__ Uf_hi,  const short* __restrict__ Uf_lo,
               const float* __restrict__ c0v,
               float* __restrict__ out)
{
    __shared__ short8 Bf[64 * 64];     // 64 frags x 64 lanes x 16B = 64 KB
    __shared__ float  Ls[RH_ * LST];   // 33.8 KB

    const int tid = threadIdx.x;
    const int l   = tid & 63;
    const int w   = tid >> 6;          // 0..7
    const int g   = l >> 5;
    const int n31 = l & 31;
    const int b   = blockIdx.x >> 4;
    const int xy0 = (blockIdx.x & 15) * NT;
    const float* zb = z + (size_t)b * C_ * XY_ + xy0;

    // ---- Phase 0: GEMM1 B-frags (z), 4 frag-pairs per wave ----
    #pragma unroll
    for (int i = 0; i < 4; ++i) {
        const int idx = w * 4 + i;     // 0..31 = kt*2 + nt
        const int kt = idx >> 1, nt = idx & 1;
        float x[8];
        short8 hi, lo;
        #pragma unroll
        for (int e = 0; e < 8; ++e)
            x[e] = zb[(size_t)(kt * 16 + 8 * g + e) * XY_ + nt * 32 + n31];
        #pragma unroll
        for (int e = 0; e < 8; ++e) {
            const short h = bf16rn(x[e]);
            hi[e] = h;
            lo[e] = bf16rn(x[e] - bf16tof(h));
        }
        Bf[(idx * 2 + 0) * 64 + l] = hi;
        Bf[(idx * 2 + 1) * 64 + l] = lo;
    }
    __syncthreads();

    // ---- Phase 1: GEMM1 (M=128 rh, N=64 pos, K=256) ----
    {
        const int mt = w & 3, nt = w >> 2;
        f32x16 aA, aB, aC;
        #pragma unroll
        for (int i = 0; i < 16; ++i) { aA[i] = 0.f; aB[i] = 0.f; aC[i] = 0.f; }

        #pragma unroll 4
        for (int kt = 0; kt < 16; ++kt) {
            const int fb = (kt * 2 + nt) * 2;
            const short8 bhi = Bf[(fb + 0) * 64 + l];
            const short8 blo = Bf[(fb + 1) * 64 + l];
            const short8 ahi = *reinterpret_cast<const short8*>(
                WLf_hi + ((size_t)(kt * 4 + mt) * 64 + l) * 8);
            const short8 alo = *reinterpret_cast<const short8*>(
                WLf_lo + ((size_t)(kt * 4 + mt) * 64 + l) * 8);
            aA = __builtin_amdgcn_mfma_f32_32x32x16_bf16(ahi, bhi, aA, 0, 0, 0);
            aB = __builtin_amdgcn_mfma_f32_32x32x16_bf16(ahi, blo, aB, 0, 0, 0);
            aC = __builtin_amdgcn_mfma_f32_32x32x16_bf16(alo, bhi, aC, 0, 0, 0);
        }
        const f32x16 acc = (aA + aB) + aC;
        #pragma unroll
        for (int r = 0; r < 16; ++r) {
            const int row = (r & 3) + 8 * (r >> 2) + 4 * g;   // verified C/D map
            Ls[(mt * 32 + row) * LST + nt * 32 + n31] = acc[r];
        }
    }
    __syncthreads();

    // ---- Phase 2: softmax over r per (h=w, pos=l), + c0 ----
    {
        float v[R_];
        float mx = -1e30f;
        #pragma unroll
        for (int r = 0; r < R_; ++r) {
            v[r] = Ls[(r * NH_ + w) * LST + l] + c0v[r * NH_ + w];
            mx = fmaxf(mx, v[r]);
        }
        float s = 0.f;
        #pragma unroll
        for (int r = 0; r < R_; ++r) { v[r] = __expf(v[r] - mx); s += v[r]; }
        const float inv = 1.f / s;
        #pragma unroll
        for (int r = 0; r < R_; ++r)
            Ls[(r * NH_ + w) * LST + l] = v[r] * inv;
    }
    __syncthreads();

    // ---- Phase 3: GEMM2 B-frags (attn), 2 frag-pairs per wave ----
    #pragma unroll
    for (int i = 0; i < 2; ++i) {
        const int idx = w * 2 + i;     // 0..15 = kt*2 + nt
        const int kt = idx >> 1, nt = idx & 1;
        float x[8];
        short8 hi, lo;
        #pragma unroll
        for (int e = 0; e < 8; ++e)
            x[e] = Ls[(kt * 16 + 8 * g + e) * LST + nt * 32 + n31];
        #pragma unroll
        for (int e = 0; e < 8; ++e) {
            const short h = bf16rn(x[e]);
            hi[e] = h;
            lo[e] = bf16rn(x[e] - bf16tof(h));
        }
        Bf[(idx * 2 + 0) * 64 + l] = hi;
        Bf[(idx * 2 + 1) * 64 + l] = lo;
    }
    __syncthreads();

    // ---- Phase 4: GEMM2 (M=256 c, N=64 pos, K=128 rh) + store ----
    {
        const int nt = w & 1, mp = w >> 1;     // mtiles {2mp, 2mp+1}
        f32x16 p0, q0, p1, q1;
        #pragma unroll
        for (int i = 0; i < 16; ++i) { p0[i] = 0.f; q0[i] = 0.f; p1[i] = 0.f; q1[i] = 0.f; }

        #pragma unroll 2
        for (int kt = 0; kt < 8; ++kt) {
            const int fb = (kt * 2 + nt) * 2;
            const short8 bhi = Bf[(fb + 0) * 64 + l];
            const short8 blo = Bf[(fb + 1) * 64 + l];
            const int t0 = kt * 8 + mp * 2, t1 = t0 + 1;
            const short8 a0h = *reinterpret_cast<const short8*>(Uf_hi + ((size_t)t0 * 64 + l) * 8);
            const short8 a0l = *reinterpret_cast<const short8*>(Uf_lo + ((size_t)t0 * 64 + l) * 8);
            const short8 a1h = *reinterpret_cast<const short8*>(Uf_hi + ((size_t)t1 * 64 + l) * 8);
            const short8 a1l = *reinterpret_cast<const short8*>(Uf_lo + ((size_t)t1 * 64 + l) * 8);
            p0 = __builtin_amdgcn_mfma_f32_32x32x16_bf16(a0h, bhi, p0, 0, 0, 0);
            q0 = __builtin_amdgcn_mfma_f32_32x32x16_bf16(a0h, blo, q0, 0, 0, 0);
            q0 = __builtin_amdgcn_mfma_f32_32x32x16_bf16(a0l, bhi, q0, 0, 0, 0);
            p1 = __builtin_amdgcn_mfma_f32_32x32x16_bf16(a1h, bhi, p1, 0, 0, 0);
            q1 = __builtin_amdgcn_mfma_f32_32x32x16_bf16(a1h, blo, q1, 0, 0, 0);
            q1 = __builtin_amdgcn_mfma_f32_32x32x16_bf16(a1l, bhi, q1, 0, 0, 0);
        }
        const f32x16 o0 = p0 + q0;
        const f32x16 o1 = p1 + q1;

        float* ob = out + (size_t)b * C_ * XY_ + xy0 + nt * 32 + n31;
        #pragma unroll
        for (int r = 0; r < 16; ++r) {
            const int row = (r & 3) + 8 * (r >> 2) + 4 * g;
            ob[(size_t)(mp * 64 + row) * XY_]      = o0[r];
            ob[(size_t)(mp * 64 + 32 + row) * XY_] = o1[r];
        }
    }
}

// ---------------------------------------------------------------------------
extern "C" void kernel_launch(void* const* d_in, const int* in_sizes, int n_in,
                              void* d_out, int out_size, void* d_ws, size_t ws_size,
                              hipStream_t stream)
{
    const float* z    = (const float*)d_in[0];
    const float* rims = (const float*)d_in[1];
    const float* Wk   = (const float*)d_in[2];
    const float* bk   = (const float*)d_in[3];
    const float* Wv   = (const float*)d_in[4];
    const float* bv   = (const float*)d_in[5];
    const float* Wq   = (const float*)d_in[6];
    const float* bq   = (const float*)d_in[7];
    const float* Wm   = (const float*)d_in[8];
    const float* bm   = (const float*)d_in[9];
    float* out = (float*)d_out;

    // ws: WLt(32768 f) | Uo(32768 f) | c0(256 f) | WLf_hi/lo | Uf_hi/lo (bf16)
    float* WLt = (float*)d_ws;
    float* Uo  = WLt + C_ * RH_;
    float* c0o = Uo + RH_ * C_;
    short* WLf_hi = (short*)(c0o + 256);
    short* WLf_lo = WLf_hi + 32768;
    short* Uf_hi  = WLf_lo + 32768;
    short* Uf_lo  = Uf_hi + 32768;

    rims_precompute<<<2 * RH_, 256, 0, stream>>>(rims, Wk, bk, Wv, bv, Wq, bq, Wm,
                                                 WLt, Uo, c0o);
    rims_pack<<<128, 64, 0, stream>>>(WLt, Uo, bm, WLf_hi, WLf_lo, Uf_hi, Uf_lo);
    rims_mfma<<<(B_ * XY_) / NT, 512, 0, stream>>>(z, WLf_hi, WLf_lo, Uf_hi, Uf_lo,
                                                   c0o, out);
}

// Round 14
// 26.441 us; speedup vs baseline: 5.2446x; 1.2970x over previous
//
#include <hip/hip_runtime.h>
#include <cstdint>
#include <cstddef>

// Dims (fixed by the reference)
#define R_   16
#define NH_  8
#define D_   32
#define C_   256
#define B_   16
#define XY_  1024      // 32*32
#define RH_  128       // R_*NH_
#define KD_  4096      // R_*NH_*D_
#define NT   32        // positions per block (main kernel)
#define PST  36        // partial/attn LDS row stride (floats)

#define LD4(p) (*reinterpret_cast<const float4*>(p))

using short8 = __attribute__((ext_vector_type(8))) short;   // 8 bf16 (4 VGPR)
using f32x16 = __attribute__((ext_vector_type(16))) float;  // MFMA 32x32 acc

__device__ __forceinline__ short bf16rn(float x) {
    unsigned u = __float_as_uint(x);
    u = (u + 0x7FFFu + ((u >> 16) & 1u)) >> 16;
    return (short)u;
}
__device__ __forceinline__ float bf16tof(short h) {
    return __uint_as_float(((unsigned)(unsigned short)h) << 16);
}

// ---------------------------------------------------------------------------
// Precompute + pack fused. 256 blocks (bid = rh*2 + half) x 256 thr.
//   half 0: k[d] = Wk[r,hD+d,:]·rims + bk  -> WLf_hi/lo fragments + c0[rh]
//   half 1: v[d] = Wv[...]·rims + bv       -> Uf_hi/lo fragments (bm/8 folded)
// Fold weights (Wq rows / Wm row-slices) are PREFETCHED into registers at
// kernel top so their latency hides under the dot phase (all VMEM in flight
// together). Fragment writes are 2B scatters -- total data is only 512 KB.
// Fragment convention (32x32x16, A and B share it): lane l -> non-K = l&31,
// K-slot e -> k = kt*16 + 8*(l>>5) + e.
// ---------------------------------------------------------------------------
__global__ __launch_bounds__(256)
void rims_precompute(const float* __restrict__ rims,
                     const float* __restrict__ Wk,
                     const float* __restrict__ bk,
                     const float* __restrict__ Wv,
                     const float* __restrict__ bv,
                     const float* __restrict__ Wq,
                     const float* __restrict__ bq,
                     const float* __restrict__ Wm,
                     const float* __restrict__ bm,
                     short* __restrict__ WLf_hi, short* __restrict__ WLf_lo,
                     short* __restrict__ Uf_hi,  short* __restrict__ Uf_lo,
                     float* __restrict__ c0o)
{
    const int bid  = blockIdx.x;       // 0..255
    const int rh   = bid >> 1;
    const int half = bid & 1;
    const int r    = rh >> 3;
    const int h    = rh & 7;
    const int tid  = threadIdx.x;
    const int c    = tid;              // 0..255

    __shared__ float kv[D_];

    // ---- prefetch fold weights into registers (latency overlaps dots) ----
    float fw[32];
    if (half == 0) {
        const float* wqp = Wq + (size_t)rh * D_ * C_ + c;
        #pragma unroll
        for (int d = 0; d < D_; ++d)
            fw[d] = wqp[(size_t)d * C_];
    } else {
        const float* wmp = Wm + (size_t)c * KD_ + rh * D_;
        #pragma unroll
        for (int d4 = 0; d4 < D_; d4 += 4) {
            const float4 m4 = LD4(wmp + d4);
            fw[d4 + 0] = m4.x; fw[d4 + 1] = m4.y;
            fw[d4 + 2] = m4.z; fw[d4 + 3] = m4.w;
        }
    }

    // ---- k/v dots: 32 dots over C=256, 8 lanes each ----
    {
        const int d    = tid >> 3;
        const int part = tid & 7;
        const float* Wsrc = (half ? Wv : Wk)
                          + ((size_t)r * 256 + h * D_ + d) * C_ + part * 32;
        const float* rr   = rims + r * C_ + part * 32;
        float a0 = 0.f, a1 = 0.f, a2 = 0.f, a3 = 0.f;
        #pragma unroll
        for (int j = 0; j < 8; ++j) {
            const float4 wv4 = LD4(Wsrc + j * 4);
            const float4 xv4 = LD4(rr + j * 4);
            a0 = fmaf(wv4.x, xv4.x, a0); a1 = fmaf(wv4.y, xv4.y, a1);
            a2 = fmaf(wv4.z, xv4.z, a2); a3 = fmaf(wv4.w, xv4.w, a3);
        }
        float acc = (a0 + a1) + (a2 + a3);
        acc += __shfl_xor(acc, 1);
        acc += __shfl_xor(acc, 2);
        acc += __shfl_xor(acc, 4);
        if (part == 0)
            kv[d] = acc + (half ? bv : bk)[r * 256 + h * D_ + d];
    }
    __syncthreads();

    // ---- fold + hi/lo split + packed-fragment scatter write ----
    {
        float x = 0.f;
        #pragma unroll
        for (int d = 0; d < D_; ++d)
            x = fmaf(kv[d], fw[d], x);

        if (half == 0) {
            // WLf tile (kt=c>>4, mt=rh>>5); lane = ((c>>3)&1)*32 + (rh&31); e = c&7
            const size_t off =
                ((size_t)((c >> 4) * 4 + (rh >> 5)) * 64
                 + ((c >> 3) & 1) * 32 + (rh & 31)) * 8 + (c & 7);
            const short hi = bf16rn(x);
            WLf_hi[off] = hi;
            WLf_lo[off] = bf16rn(x - bf16tof(hi));

            if (tid < D_) {
                float s = kv[tid] * bq[rh * D_ + tid];
                s += __shfl_xor(s, 1);  s += __shfl_xor(s, 2);  s += __shfl_xor(s, 4);
                s += __shfl_xor(s, 8);  s += __shfl_xor(s, 16);
                if (tid == 0) c0o[rh] = s;
            }
        } else {
            x += 0.125f * bm[c];       // bm folded: sum_rh attn == NH_ == 8
            // Uf tile (kt=rh>>4, mt=c>>5); lane = ((rh>>3)&1)*32 + (c&31); e = rh&7
            const size_t off =
                ((size_t)((rh >> 4) * 8 + (c >> 5)) * 64
                 + ((rh >> 3) & 1) * 32 + (c & 31)) * 8 + (rh & 7);
            const short hi = bf16rn(x);
            Uf_hi[off] = hi;
            Uf_lo[off] = bf16rn(x - bf16tof(hi));
        }
    }
}

// ---------------------------------------------------------------------------
// MFMA main: 512 blocks x 512 thr (8 waves), 32 positions per block.
// LDS 68 KB -> 2 blocks/CU co-resident (barriers of one block hide under the
// other block's MFMA). Exact bf16-split (3 products) on mfma_f32_32x32x16.
//   Phase 0: z B-frags (kt 0..15, hi/lo) -> Bf          [2 frag-pairs/wave]
//   Phase 1: GEMM1 split-K: wave (mt=w&3, ks=w>>2) does kt in [8ks,8ks+8)
//            -> partials P[ks]                           [24 MFMA/wave]
//   Phase 2: softmax over r (P0+P1+c0), attn -> P0      [tid<256]
//   Phase 3: attn B-frags (kt 0..7) -> Bf (reused)      [1 frag-pair/wave]
//   Phase 4: GEMM2: wave w -> c tile mt=w, K=128        [24 MFMA/wave]
// A-frags stream from packed global: per-lane coalesced b128 VMEM (counted,
// compiler-pipelined). C/D map (verified m74/m101): row=(r&3)+8(r>>2)+4g.
// ---------------------------------------------------------------------------
__global__ __launch_bounds__(512, 4)
void rims_mfma(const float* __restrict__ z,
               const short* __restrict__ WLf_hi, const short* __restrict__ WLf_lo,
               const short* __restrict__ Uf_hi,  const short* __restrict__ Uf_lo,
               const float* __restrict__ c0v,
               float* __restrict__ out)
{
    __shared__ short8 Bf[32 * 64];       // 32 frags x 1 KB = 32 KB
    __shared__ float  P0[RH_ * PST];     // 18 KB
    __shared__ float  P1[RH_ * PST];     // 18 KB

    const int tid = threadIdx.x;
    const int l   = tid & 63;
    const int w   = tid >> 6;            // 0..7
    const int g   = l >> 5;
    const int n31 = l & 31;
    const int b   = blockIdx.x >> 5;
    const int xy0 = (blockIdx.x & 31) * NT;
    const float* zb = z + (size_t)b * C_ * XY_ + xy0;

    // ---- Phase 0: z B-frags (2 frag-pairs per wave) ----
    #pragma unroll
    for (int i = 0; i < 2; ++i) {
        const int kt = w * 2 + i;        // 0..15
        float x[8];
        short8 hi, lo;
        #pragma unroll
        for (int e = 0; e < 8; ++e)
            x[e] = zb[(size_t)(kt * 16 + 8 * g + e) * XY_ + n31];
        #pragma unroll
        for (int e = 0; e < 8; ++e) {
            const short hh = bf16rn(x[e]);
            hi[e] = hh;
            lo[e] = bf16rn(x[e] - bf16tof(hh));
        }
        Bf[(kt * 2 + 0) * 64 + l] = hi;
        Bf[(kt * 2 + 1) * 64 + l] = lo;
    }
    __syncthreads();

    // ---- Phase 1: GEMM1 split-K (M=128 rh, N=32, K=256) ----
    {
        const int mt = w & 3, ks = w >> 2;
        f32x16 aA, aB, aC;
        #pragma unroll
        for (int i = 0; i < 16; ++i) { aA[i] = 0.f; aB[i] = 0.f; aC[i] = 0.f; }

        #pragma unroll 2
        for (int k8 = 0; k8 < 8; ++k8) {
            const int kt = ks * 8 + k8;
            const short8 bhi = Bf[(kt * 2 + 0) * 64 + l];
            const short8 blo = Bf[(kt * 2 + 1) * 64 + l];
            const short8 ahi = *reinterpret_cast<const short8*>(
                WLf_hi + ((size_t)(kt * 4 + mt) * 64 + l) * 8);
            const short8 alo = *reinterpret_cast<const short8*>(
                WLf_lo + ((size_t)(kt * 4 + mt) * 64 + l) * 8);
            aA = __builtin_amdgcn_mfma_f32_32x32x16_bf16(ahi, bhi, aA, 0, 0, 0);
            aB = __builtin_amdgcn_mfma_f32_32x32x16_bf16(ahi, blo, aB, 0, 0, 0);
            aC = __builtin_amdgcn_mfma_f32_32x32x16_bf16(alo, bhi, aC, 0, 0, 0);
        }
        const f32x16 acc = (aA + aB) + aC;
        float* Pd = ks ? P1 : P0;
        #pragma unroll
        for (int r = 0; r < 16; ++r) {
            const int row = (r & 3) + 8 * (r >> 2) + 4 * g;
            Pd[(mt * 32 + row) * PST + n31] = acc[r];
        }
    }
    __syncthreads();

    // ---- Phase 2: softmax over r per (h, p), folds split-K + c0 ----
    if (tid < 256) {
        const int h = tid >> 5;          // 0..7
        const int p = tid & 31;
        float v[R_];
        float mx = -1e30f;
        #pragma unroll
        for (int r = 0; r < R_; ++r) {
            const int row = r * NH_ + h;
            v[r] = (P0[row * PST + p] + P1[row * PST + p]) + c0v[row];
            mx = fmaxf(mx, v[r]);
        }
        float s = 0.f;
        #pragma unroll
        for (int r = 0; r < R_; ++r) { v[r] = __expf(v[r] - mx); s += v[r]; }
        const float inv = 1.f / s;
        #pragma unroll
        for (int r = 0; r < R_; ++r)
            P0[(r * NH_ + h) * PST + p] = v[r] * inv;
    }
    __syncthreads();

    // ---- Phase 3: attn B-frags (1 frag-pair per wave) ----
    {
        const int kt = w;                // 0..7
        float x[8];
        short8 hi, lo;
        #pragma unroll
        for (int e = 0; e < 8; ++e)
            x[e] = P0[(kt * 16 + 8 * g + e) * PST + n31];
        #pragma unroll
        for (int e = 0; e < 8; ++e) {
            const short hh = bf16rn(x[e]);
            hi[e] = hh;
            lo[e] = bf16rn(x[e] - bf16tof(hh));
        }
        Bf[(kt * 2 + 0) * 64 + l] = hi;
        Bf[(kt * 2 + 1) * 64 + l] = lo;
    }
    __syncthreads();

    // ---- Phase 4: GEMM2 (M=256 c, N=32, K=128) + store ----
    {
        const int mt = w;                // c tile [32w, 32w+32)
        f32x16 p, q;
        #pragma unroll
        for (int i = 0; i < 16; ++i) { p[i] = 0.f; q[i] = 0.f; }

        #pragma unroll 2
        for (int kt = 0; kt < 8; ++kt) {
            const short8 bhi = Bf[(kt * 2 + 0) * 64 + l];
            const short8 blo = Bf[(kt * 2 + 1) * 64 + l];
            const short8 ahi = *reinterpret_cast<const short8*>(
                Uf_hi + ((size_t)(kt * 8 + mt) * 64 + l) * 8);
            const short8 alo = *reinterpret_cast<const short8*>(
                Uf_lo + ((size_t)(kt * 8 + mt) * 64 + l) * 8);
            p = __builtin_amdgcn_mfma_f32_32x32x16_bf16(ahi, bhi, p, 0, 0, 0);
            q = __builtin_amdgcn_mfma_f32_32x32x16_bf16(ahi, blo, q, 0, 0, 0);
            q = __builtin_amdgcn_mfma_f32_32x32x16_bf16(alo, bhi, q, 0, 0, 0);
        }
        const f32x16 o = p + q;

        float* ob = out + (size_t)b * C_ * XY_ + xy0 + n31;
        #pragma unroll
        for (int r = 0; r < 16; ++r) {
            const int row = (r & 3) + 8 * (r >> 2) + 4 * g;
            ob[(size_t)(mt * 32 + row) * XY_] = o[r];
        }
    }
}

// ---------------------------------------------------------------------------
extern "C" void kernel_launch(void* const* d_in, const int* in_sizes, int n_in,
                              void* d_out, int out_size, void* d_ws, size_t ws_size,
                              hipStream_t stream)
{
    const float* z    = (const float*)d_in[0];
    const float* rims = (const float*)d_in[1];
    const float* Wk   = (const float*)d_in[2];
    const float* bk   = (const float*)d_in[3];
    const float* Wv   = (const float*)d_in[4];
    const float* bv   = (const float*)d_in[5];
    const float* Wq   = (const float*)d_in[6];
    const float* bq   = (const float*)d_in[7];
    const float* Wm   = (const float*)d_in[8];
    const float* bm   = (const float*)d_in[9];
    float* out = (float*)d_out;

    // ws: WLf_hi/lo (32768 shorts each) | Uf_hi/lo | c0 (256 f)
    short* WLf_hi = (short*)d_ws;
    short* WLf_lo = WLf_hi + 32768;
    short* Uf_hi  = WLf_lo + 32768;
    short* Uf_lo  = Uf_hi + 32768;
    float* c0o    = (float*)(Uf_lo + 32768);

    rims_precompute<<<2 * RH_, 256, 0, stream>>>(rims, Wk, bk, Wv, bv, Wq, bq,
                                                 Wm, bm, WLf_hi, WLf_lo,
                                                 Uf_hi, Uf_lo, c0o);
    rims_mfma<<<(B_ * XY_) / NT, 512, 0, stream>>>(z, WLf_hi, WLf_lo,
                                                   Uf_hi, Uf_lo, c0o, out);
}

// Round 15
// 25.473 us; speedup vs baseline: 5.4440x; 1.0380x over previous
//
#include <hip/hip_runtime.h>
#include <cstdint>
#include <cstddef>

// Dims (fixed by the reference)
#define R_   16
#define NH_  8
#define D_   32
#define C_   256
#define B_   16
#define XY_  1024      // 32*32
#define RH_  128       // R_*NH_
#define KD_  4096      // R_*NH_*D_
#define NT   32        // positions per block (main kernel)
#define PST  32        // partial/attn LDS row stride (floats; 2-way bank = free)

#define LD4(p) (*reinterpret_cast<const float4*>(p))

using short8 = __attribute__((ext_vector_type(8))) short;   // 8 bf16 (4 VGPR)
using f32x16 = __attribute__((ext_vector_type(16))) float;  // MFMA 32x32 acc

__device__ __forceinline__ short bf16rn(float x) {
    unsigned u = __float_as_uint(x);
    u = (u + 0x7FFFu + ((u >> 16) & 1u)) >> 16;
    return (short)u;
}
__device__ __forceinline__ float bf16tof(short h) {
    return __uint_as_float(((unsigned)(unsigned short)h) << 16);
}

// ---------------------------------------------------------------------------
// Precompute + pack fused. 256 blocks (bid = rh*2 + half) x 256 thr.
//   half 0: k[d] = Wk[r,hD+d,:]·rims + bk  -> WLf_hi/lo fragments + c0[rh]
//   half 1: v[d] = Wv[...]·rims + bv       -> Uf_hi/lo fragments (bm/8 folded)
// Dot-phase loads are line-coalesced: at iter j the 8 lanes of one dot read
// cols [j*32 + part*4 .. +4) -> one fully-consumed 128 B line per instr
// (the old part*32 mapping used 16 B of 64 different lines per instr).
// Fold weights prefetched into registers at kernel top (latency under dots).
// Fragment convention (32x32x16, A and B share it): lane l -> non-K = l&31,
// K-slot e -> k = kt*16 + 8*(l>>5) + e.
// ---------------------------------------------------------------------------
__global__ __launch_bounds__(256)
void rims_precompute(const float* __restrict__ rims,
                     const float* __restrict__ Wk,
                     const float* __restrict__ bk,
                     const float* __restrict__ Wv,
                     const float* __restrict__ bv,
                     const float* __restrict__ Wq,
                     const float* __restrict__ bq,
                     const float* __restrict__ Wm,
                     const float* __restrict__ bm,
                     short* __restrict__ WLf_hi, short* __restrict__ WLf_lo,
                     short* __restrict__ Uf_hi,  short* __restrict__ Uf_lo,
                     float* __restrict__ c0o)
{
    const int bid  = blockIdx.x;       // 0..255
    const int rh   = bid >> 1;
    const int half = bid & 1;
    const int r    = rh >> 3;
    const int h    = rh & 7;
    const int tid  = threadIdx.x;
    const int c    = tid;              // 0..255

    __shared__ float kv[D_];

    // ---- prefetch fold weights into registers (latency overlaps dots) ----
    float fw[32];
    if (half == 0) {
        const float* wqp = Wq + (size_t)rh * D_ * C_ + c;
        #pragma unroll
        for (int d = 0; d < D_; ++d)
            fw[d] = wqp[(size_t)d * C_];
    } else {
        const float* wmp = Wm + (size_t)c * KD_ + rh * D_;
        #pragma unroll
        for (int d4 = 0; d4 < D_; d4 += 4) {
            const float4 m4 = LD4(wmp + d4);
            fw[d4 + 0] = m4.x; fw[d4 + 1] = m4.y;
            fw[d4 + 2] = m4.z; fw[d4 + 3] = m4.w;
        }
    }

    // ---- k/v dots: 32 dots over C=256, 8 lanes each, line-coalesced ----
    {
        const int d    = tid >> 3;
        const int part = tid & 7;
        const float* Wsrc = (half ? Wv : Wk)
                          + ((size_t)r * 256 + h * D_ + d) * C_ + part * 4;
        const float* rr   = rims + r * C_ + part * 4;
        float a0 = 0.f, a1 = 0.f, a2 = 0.f, a3 = 0.f;
        #pragma unroll
        for (int j = 0; j < 8; ++j) {
            const float4 wv4 = LD4(Wsrc + j * 32);
            const float4 xv4 = LD4(rr + j * 32);
            a0 = fmaf(wv4.x, xv4.x, a0); a1 = fmaf(wv4.y, xv4.y, a1);
            a2 = fmaf(wv4.z, xv4.z, a2); a3 = fmaf(wv4.w, xv4.w, a3);
        }
        float acc = (a0 + a1) + (a2 + a3);
        acc += __shfl_xor(acc, 1);
        acc += __shfl_xor(acc, 2);
        acc += __shfl_xor(acc, 4);
        if (part == 0)
            kv[d] = acc + (half ? bv : bk)[r * 256 + h * D_ + d];
    }
    __syncthreads();

    // ---- fold + hi/lo split + packed-fragment scatter write ----
    {
        float x = 0.f;
        #pragma unroll
        for (int d = 0; d < D_; ++d)
            x = fmaf(kv[d], fw[d], x);

        if (half == 0) {
            // WLf tile (kt=c>>4, mt=rh>>5); lane = ((c>>3)&1)*32 + (rh&31); e = c&7
            const size_t off =
                ((size_t)((c >> 4) * 4 + (rh >> 5)) * 64
                 + ((c >> 3) & 1) * 32 + (rh & 31)) * 8 + (c & 7);
            const short hi = bf16rn(x);
            WLf_hi[off] = hi;
            WLf_lo[off] = bf16rn(x - bf16tof(hi));

            if (tid < D_) {
                float s = kv[tid] * bq[rh * D_ + tid];
                s += __shfl_xor(s, 1);  s += __shfl_xor(s, 2);  s += __shfl_xor(s, 4);
                s += __shfl_xor(s, 8);  s += __shfl_xor(s, 16);
                if (tid == 0) c0o[rh] = s;
            }
        } else {
            x += 0.125f * bm[c];       // bm folded: sum_rh attn == NH_ == 8
            // Uf tile (kt=rh>>4, mt=c>>5); lane = ((rh>>3)&1)*32 + (c&31); e = rh&7
            const size_t off =
                ((size_t)((rh >> 4) * 8 + (c >> 5)) * 64
                 + ((rh >> 3) & 1) * 32 + (c & 31)) * 8 + (rh & 7);
            const short hi = bf16rn(x);
            Uf_hi[off] = hi;
            Uf_lo[off] = bf16rn(x - bf16tof(hi));
        }
    }
}

// ---------------------------------------------------------------------------
// MFMA main: 512 blocks x 512 thr (8 waves), 32 positions per block.
// LDS 64 KB -> 2 blocks/CU co-resident. Exact bf16-split (hi+lo, 3 products)
// on mfma_f32_32x32x16_bf16; cross terms share one accumulator (VGPR -16).
//   Phase 0: z B-frags (kt 0..15, hi/lo) -> Bf          [2 frag-pairs/wave]
//   Phase 1: GEMM1 split-K: wave (mt=w&3, ks=w>>2), kt in [8ks,8ks+8)
//            -> partials P[ks]                           [24 MFMA/wave]
//   Phase 2: softmax over r (P0+P1+c0), attn -> P0      [tid<256]
//   Phase 3: attn B-frags (kt 0..7) -> Bf (reused)      [1 frag-pair/wave]
//   Phase 4: GEMM2: wave w -> c tile mt=w, K=128        [24 MFMA/wave]
// A-frags stream from packed global: per-lane coalesced b128 VMEM (counted,
// compiler-pipelined). C/D map (verified m74/m101): row=(r&3)+8(r>>2)+4g.
// All P-buffer access = 2 lanes/bank (free, m136).
// ---------------------------------------------------------------------------
__global__ __launch_bounds__(512, 4)
void rims_mfma(const float* __restrict__ z,
               const short* __restrict__ WLf_hi, const short* __restrict__ WLf_lo,
               const short* __restrict__ Uf_hi,  const short* __restrict__ Uf_lo,
               const float* __restrict__ c0v,
               float* __restrict__ out)
{
    __shared__ short8 Bf[32 * 64];       // 32 frags x 1 KB = 32 KB
    __shared__ float  P0[RH_ * PST];     // 16 KB
    __shared__ float  P1[RH_ * PST];     // 16 KB

    const int tid = threadIdx.x;
    const int l   = tid & 63;
    const int w   = tid >> 6;            // 0..7
    const int g   = l >> 5;
    const int n31 = l & 31;
    const int b   = blockIdx.x >> 5;
    const int xy0 = (blockIdx.x & 31) * NT;
    const float* zb = z + (size_t)b * C_ * XY_ + xy0;

    // ---- Phase 0: z B-frags (2 frag-pairs per wave) ----
    #pragma unroll
    for (int i = 0; i < 2; ++i) {
        const int kt = w * 2 + i;        // 0..15
        float x[8];
        short8 hi, lo;
        #pragma unroll
        for (int e = 0; e < 8; ++e)
            x[e] = zb[(size_t)(kt * 16 + 8 * g + e) * XY_ + n31];
        #pragma unroll
        for (int e = 0; e < 8; ++e) {
            const short hh = bf16rn(x[e]);
            hi[e] = hh;
            lo[e] = bf16rn(x[e] - bf16tof(hh));
        }
        Bf[(kt * 2 + 0) * 64 + l] = hi;
        Bf[(kt * 2 + 1) * 64 + l] = lo;
    }
    __syncthreads();

    // ---- Phase 1: GEMM1 split-K (M=128 rh, N=32, K=256) ----
    {
        const int mt = w & 3, ks = w >> 2;
        f32x16 aA, aB;
        #pragma unroll
        for (int i = 0; i < 16; ++i) { aA[i] = 0.f; aB[i] = 0.f; }

        #pragma unroll 2
        for (int k8 = 0; k8 < 8; ++k8) {
            const int kt = ks * 8 + k8;
            const short8 bhi = Bf[(kt * 2 + 0) * 64 + l];
            const short8 blo = Bf[(kt * 2 + 1) * 64 + l];
            const short8 ahi = *reinterpret_cast<const short8*>(
                WLf_hi + ((size_t)(kt * 4 + mt) * 64 + l) * 8);
            const short8 alo = *reinterpret_cast<const short8*>(
                WLf_lo + ((size_t)(kt * 4 + mt) * 64 + l) * 8);
            aA = __builtin_amdgcn_mfma_f32_32x32x16_bf16(ahi, bhi, aA, 0, 0, 0);
            aB = __builtin_amdgcn_mfma_f32_32x32x16_bf16(ahi, blo, aB, 0, 0, 0);
            aB = __builtin_amdgcn_mfma_f32_32x32x16_bf16(alo, bhi, aB, 0, 0, 0);
        }
        const f32x16 acc = aA + aB;
        float* Pd = ks ? P1 : P0;
        #pragma unroll
        for (int r = 0; r < 16; ++r) {
            const int row = (r & 3) + 8 * (r >> 2) + 4 * g;
            Pd[(mt * 32 + row) * PST + n31] = acc[r];
        }
    }
    __syncthreads();

    // ---- Phase 2: softmax over r per (h, p), folds split-K + c0 ----
    if (tid < 256) {
        const int h = tid >> 5;          // 0..7
        const int p = tid & 31;
        float v[R_];
        float mx = -1e30f;
        #pragma unroll
        for (int r = 0; r < R_; ++r) {
            const int row = r * NH_ + h;
            v[r] = (P0[row * PST + p] + P1[row * PST + p]) + c0v[row];
            mx = fmaxf(mx, v[r]);
        }
        float s = 0.f;
        #pragma unroll
        for (int r = 0; r < R_; ++r) { v[r] = __expf(v[r] - mx); s += v[r]; }
        const float inv = 1.f / s;
        #pragma unroll
        for (int r = 0; r < R_; ++r)
            P0[(r * NH_ + h) * PST + p] = v[r] * inv;
    }
    __syncthreads();

    // ---- Phase 3: attn B-frags (1 frag-pair per wave) ----
    {
        const int kt = w;                // 0..7
        float x[8];
        short8 hi, lo;
        #pragma unroll
        for (int e = 0; e < 8; ++e)
            x[e] = P0[(kt * 16 + 8 * g + e) * PST + n31];
        #pragma unroll
        for (int e = 0; e < 8; ++e) {
            const short hh = bf16rn(x[e]);
            hi[e] = hh;
            lo[e] = bf16rn(x[e] - bf16tof(hh));
        }
        Bf[(kt * 2 + 0) * 64 + l] = hi;
        Bf[(kt * 2 + 1) * 64 + l] = lo;
    }
    __syncthreads();

    // ---- Phase 4: GEMM2 (M=256 c, N=32, K=128) + store ----
    {
        const int mt = w;                // c tile [32w, 32w+32)
        f32x16 p, q;
        #pragma unroll
        for (int i = 0; i < 16; ++i) { p[i] = 0.f; q[i] = 0.f; }

        #pragma unroll 2
        for (int kt = 0; kt < 8; ++kt) {
            const short8 bhi = Bf[(kt * 2 + 0) * 64 + l];
            const short8 blo = Bf[(kt * 2 + 1) * 64 + l];
            const short8 ahi = *reinterpret_cast<const short8*>(
                Uf_hi + ((size_t)(kt * 8 + mt) * 64 + l) * 8);
            const short8 alo = *reinterpret_cast<const short8*>(
                Uf_lo + ((size_t)(kt * 8 + mt) * 64 + l) * 8);
            p = __builtin_amdgcn_mfma_f32_32x32x16_bf16(ahi, bhi, p, 0, 0, 0);
            q = __builtin_amdgcn_mfma_f32_32x32x16_bf16(ahi, blo, q, 0, 0, 0);
            q = __builtin_amdgcn_mfma_f32_32x32x16_bf16(alo, bhi, q, 0, 0, 0);
        }
        const f32x16 o = p + q;

        float* ob = out + (size_t)b * C_ * XY_ + xy0 + n31;
        #pragma unroll
        for (int r = 0; r < 16; ++r) {
            const int row = (r & 3) + 8 * (r >> 2) + 4 * g;
            ob[(size_t)(mt * 32 + row) * XY_] = o[r];
        }
    }
}

// ---------------------------------------------------------------------------
extern "C" void kernel_launch(void* const* d_in, const int* in_sizes, int n_in,
                              void* d_out, int out_size, void* d_ws, size_t ws_size,
                              hipStream_t stream)
{
    const float* z    = (const float*)d_in[0];
    const float* rims = (const float*)d_in[1];
    const float* Wk   = (const float*)d_in[2];
    const float* bk   = (const float*)d_in[3];
    const float* Wv   = (const float*)d_in[4];
    const float* bv   = (const float*)d_in[5];
    const float* Wq   = (const float*)d_in[6];
    const float* bq   = (const float*)d_in[7];
    const float* Wm   = (const float*)d_in[8];
    const float* bm   = (const float*)d_in[9];
    float* out = (float*)d_out;

    // ws: WLf_hi/lo (32768 shorts each) | Uf_hi/lo | c0 (256 f)
    short* WLf_hi = (short*)d_ws;
    short* WLf_lo = WLf_hi + 32768;
    short* Uf_hi  = WLf_lo + 32768;
    short* Uf_lo  = Uf_hi + 32768;
    float* c0o    = (float*)(Uf_lo + 32768);

    rims_precompute<<<2 * RH_, 256, 0, stream>>>(rims, Wk, bk, Wv, bv, Wq, bq,
                                                 Wm, bm, WLf_hi, WLf_lo,
                                                 Uf_hi, Uf_lo, c0o);
    rims_mfma<<<(B_ * XY_) / NT, 512, 0, stream>>>(z, WLf_hi, WLf_lo,
                                                   Uf_hi, Uf_lo, c0o, out);
}

// Round 16
// 22.103 us; speedup vs baseline: 6.2741x; 1.1525x over previous
//
#include <hip/hip_runtime.h>
#include <cstdint>
#include <cstddef>

// Dims (fixed by the reference)
#define R_   16
#define NH_  8
#define D_   32
#define C_   256
#define B_   16
#define XY_  1024      // 32*32
#define RH_  128       // R_*NH_
#define KD_  4096      // R_*NH_*D_
#define NT   32        // positions per block (main kernel)
#define PST  32        // partial LDS row stride (floats; 2-way bank = free)

#define LD4(p) (*reinterpret_cast<const float4*>(p))

using short8 = __attribute__((ext_vector_type(8))) short;   // 8 bf16 (4 VGPR)
using f32x16 = __attribute__((ext_vector_type(16))) float;  // MFMA 32x32 acc

__device__ __forceinline__ short bf16rn(float x) {
    unsigned u = __float_as_uint(x);
    u = (u + 0x7FFFu + ((u >> 16) & 1u)) >> 16;
    return (short)u;
}
__device__ __forceinline__ float bf16tof(short h) {
    return __uint_as_float(((unsigned)(unsigned short)h) << 16);
}

// ---------------------------------------------------------------------------
// Precompute + pack fused, 512 threads (8 waves -> 2/SIMD, was 1/SIMD).
// 256 blocks (bid = rh*2 + half).
//   dots: 32 dots x 16 lanes (4 float4 each), xor-reduce 1,2,4,8.
//   fold: lane pair (c, dh): each sums its 16-d half, shfl_xor(1) combines;
//         dh=0 lane writes hi fragment, dh=1 lane writes lo fragment.
// Fragment convention (32x32x16, A and B share it): lane l -> non-K = l&31,
// K-slot e -> k = kt*16 + 8*(l>>5) + e.  (same as R15; verified)
// ---------------------------------------------------------------------------
__global__ __launch_bounds__(512)
void rims_precompute(const float* __restrict__ rims,
                     const float* __restrict__ Wk,
                     const float* __restrict__ bk,
                     const float* __restrict__ Wv,
                     const float* __restrict__ bv,
                     const float* __restrict__ Wq,
                     const float* __restrict__ bq,
                     const float* __restrict__ Wm,
                     const float* __restrict__ bm,
                     short* __restrict__ WLf_hi, short* __restrict__ WLf_lo,
                     short* __restrict__ Uf_hi,  short* __restrict__ Uf_lo,
                     float* __restrict__ c0o)
{
    const int bid  = blockIdx.x;       // 0..255
    const int rh   = bid >> 1;
    const int half = bid & 1;
    const int r    = rh >> 3;
    const int h    = rh & 7;
    const int tid  = threadIdx.x;      // 0..511
    const int c    = tid >> 1;         // 0..255
    const int dh   = tid & 1;          // d-half selector

    __shared__ float kv[D_];

    // ---- prefetch fold weights (16 per lane; latency overlaps dots) ----
    float fw[16];
    if (half == 0) {
        const float* wqp = Wq + ((size_t)rh * D_ + dh * 16) * C_ + c;
        #pragma unroll
        for (int i = 0; i < 16; ++i)
            fw[i] = wqp[(size_t)i * C_];
    } else {
        const float* wmp = Wm + (size_t)c * KD_ + rh * D_ + dh * 16;
        #pragma unroll
        for (int i4 = 0; i4 < 16; i4 += 4) {
            const float4 m4 = LD4(wmp + i4);
            fw[i4 + 0] = m4.x; fw[i4 + 1] = m4.y;
            fw[i4 + 2] = m4.z; fw[i4 + 3] = m4.w;
        }
    }

    // ---- k/v dots: 32 dots x 16 lanes, line-coalesced ----
    {
        const int d    = tid >> 4;     // 0..31
        const int part = tid & 15;     // 0..15
        const float* Wsrc = (half ? Wv : Wk)
                          + ((size_t)r * 256 + h * D_ + d) * C_ + part * 4;
        const float* rr   = rims + r * C_ + part * 4;
        float a0 = 0.f, a1 = 0.f, a2 = 0.f, a3 = 0.f;
        #pragma unroll
        for (int j = 0; j < 4; ++j) {
            const float4 w4 = LD4(Wsrc + j * 64);
            const float4 x4 = LD4(rr + j * 64);
            a0 = fmaf(w4.x, x4.x, a0); a1 = fmaf(w4.y, x4.y, a1);
            a2 = fmaf(w4.z, x4.z, a2); a3 = fmaf(w4.w, x4.w, a3);
        }
        float acc = (a0 + a1) + (a2 + a3);
        acc += __shfl_xor(acc, 1);
        acc += __shfl_xor(acc, 2);
        acc += __shfl_xor(acc, 4);
        acc += __shfl_xor(acc, 8);
        if (part == 0)
            kv[d] = acc + (half ? bv : bk)[r * 256 + h * D_ + d];
    }
    __syncthreads();

    // ---- fold (split over lane pair) + hi/lo split + fragment write ----
    {
        float x = 0.f;
        #pragma unroll
        for (int i = 0; i < 16; ++i)
            x = fmaf(kv[dh * 16 + i], fw[i], x);
        x += __shfl_xor(x, 1);         // combine d-halves (adjacent lanes)

        if (half == 0) {
            // WLf tile (kt=c>>4, mt=rh>>5); lane=((c>>3)&1)*32+(rh&31); e=c&7
            const size_t off =
                ((size_t)((c >> 4) * 4 + (rh >> 5)) * 64
                 + ((c >> 3) & 1) * 32 + (rh & 31)) * 8 + (c & 7);
            const short hi = bf16rn(x);
            if (dh == 0) WLf_hi[off] = hi;
            else         WLf_lo[off] = bf16rn(x - bf16tof(hi));
        } else {
            x += 0.125f * bm[c];       // bm folded: sum_rh attn == NH_ == 8
            // Uf tile (kt=rh>>4, mt=c>>5); lane=((rh>>3)&1)*32+(c&31); e=rh&7
            const size_t off =
                ((size_t)((rh >> 4) * 8 + (c >> 5)) * 64
                 + ((rh >> 3) & 1) * 32 + (c & 31)) * 8 + (rh & 7);
            const short hi = bf16rn(x);
            if (dh == 0) Uf_hi[off] = hi;
            else         Uf_lo[off] = bf16rn(x - bf16tof(hi));
        }
    }

    // ---- c0[rh] = k · bq slice ----
    if (half == 0 && tid < D_) {
        float s = kv[tid] * bq[rh * D_ + tid];
        s += __shfl_xor(s, 1);  s += __shfl_xor(s, 2);  s += __shfl_xor(s, 4);
        s += __shfl_xor(s, 8);  s += __shfl_xor(s, 16);
        if (tid == 0) c0o[rh] = s;
    }
}

// ---------------------------------------------------------------------------
// MFMA main: 512 blocks x 512 thr (8 waves), 32 positions per block.
// LDS 64 KB -> 2 blocks/CU. Exact bf16-split (hi+lo, 3 products).
//   Phase 0: z B-frags (kt 0..15) -> Bf;  prefetch GEMM1 kt0 A-frags
//   Phase 1: GEMM1 split-K (mt=w&3, ks=w>>2) -> P0/P1 (+c0 on ks=0)
//   Phase 2 (fused): softmax over r, then scatter attn bf16 hi/lo DIRECTLY
//            into Bf fragments (kt=r>>1, g=r&1, e=h, lane=(r&1)*32+p);
//            all waves prefetch GEMM2 kt0 A-frags before the barrier
//   Phase 3: GEMM2 (mt=w, K=128) + store
// 3 barriers (was 4). A-frags: per-lane coalesced b128 VMEM, L2-hot.
// C/D map (verified m74/m101): row=(r&3)+8(r>>2)+4g.
// ---------------------------------------------------------------------------
__global__ __launch_bounds__(512, 4)
void rims_mfma(const float* __restrict__ z,
               const short* __restrict__ WLf_hi, const short* __restrict__ WLf_lo,
               const short* __restrict__ Uf_hi,  const short* __restrict__ Uf_lo,
               const float* __restrict__ c0v,
               float* __restrict__ out)
{
    __shared__ short8 Bf[32 * 64];       // 32 KB
    __shared__ float  P0[RH_ * PST];     // 16 KB
    __shared__ float  P1[RH_ * PST];     // 16 KB

    const int tid = threadIdx.x;
    const int l   = tid & 63;
    const int w   = tid >> 6;            // 0..7
    const int g   = l >> 5;
    const int n31 = l & 31;
    const int b   = blockIdx.x >> 5;
    const int xy0 = (blockIdx.x & 31) * NT;
    const float* zb = z + (size_t)b * C_ * XY_ + xy0;

    const int mt1 = w & 3, ks = w >> 2;  // GEMM1 assignment
    const int kt0 = ks * 8;

    // ---- Phase 0: z B-frags (2 frag-pairs per wave) ----
    #pragma unroll
    for (int i = 0; i < 2; ++i) {
        const int kt = w * 2 + i;        // 0..15
        float x[8];
        short8 hi, lo;
        #pragma unroll
        for (int e = 0; e < 8; ++e)
            x[e] = zb[(size_t)(kt * 16 + 8 * g + e) * XY_ + n31];
        #pragma unroll
        for (int e = 0; e < 8; ++e) {
            const short hh = bf16rn(x[e]);
            hi[e] = hh;
            lo[e] = bf16rn(x[e] - bf16tof(hh));
        }
        Bf[(kt * 2 + 0) * 64 + l] = hi;
        Bf[(kt * 2 + 1) * 64 + l] = lo;
    }

    // prefetch first GEMM1 A-frag pair (global only -> legal before barrier)
    const short8 w0h = *reinterpret_cast<const short8*>(
        WLf_hi + ((size_t)(kt0 * 4 + mt1) * 64 + l) * 8);
    const short8 w0l = *reinterpret_cast<const short8*>(
        WLf_lo + ((size_t)(kt0 * 4 + mt1) * 64 + l) * 8);
    __syncthreads();

    // ---- Phase 1: GEMM1 split-K (M=128 rh, N=32, K=256) ----
    {
        f32x16 aA, aB;
        #pragma unroll
        for (int i = 0; i < 16; ++i) { aA[i] = 0.f; aB[i] = 0.f; }

        // peeled kt0 (A-frags already in registers)
        {
            const short8 bhi = Bf[(kt0 * 2 + 0) * 64 + l];
            const short8 blo = Bf[(kt0 * 2 + 1) * 64 + l];
            aA = __builtin_amdgcn_mfma_f32_32x32x16_bf16(w0h, bhi, aA, 0, 0, 0);
            aB = __builtin_amdgcn_mfma_f32_32x32x16_bf16(w0h, blo, aB, 0, 0, 0);
            aB = __builtin_amdgcn_mfma_f32_32x32x16_bf16(w0l, bhi, aB, 0, 0, 0);
        }
        #pragma unroll 2
        for (int k8 = 1; k8 < 8; ++k8) {
            const int kt = kt0 + k8;
            const short8 bhi = Bf[(kt * 2 + 0) * 64 + l];
            const short8 blo = Bf[(kt * 2 + 1) * 64 + l];
            const short8 ahi = *reinterpret_cast<const short8*>(
                WLf_hi + ((size_t)(kt * 4 + mt1) * 64 + l) * 8);
            const short8 alo = *reinterpret_cast<const short8*>(
                WLf_lo + ((size_t)(kt * 4 + mt1) * 64 + l) * 8);
            aA = __builtin_amdgcn_mfma_f32_32x32x16_bf16(ahi, bhi, aA, 0, 0, 0);
            aB = __builtin_amdgcn_mfma_f32_32x32x16_bf16(ahi, blo, aB, 0, 0, 0);
            aB = __builtin_amdgcn_mfma_f32_32x32x16_bf16(alo, bhi, aB, 0, 0, 0);
        }
        const f32x16 acc = aA + aB;
        if (ks == 0) {
            #pragma unroll
            for (int r = 0; r < 16; ++r) {
                const int row = (r & 3) + 8 * (r >> 2) + 4 * g;
                const int rg  = mt1 * 32 + row;
                P0[rg * PST + n31] = acc[r] + c0v[rg];   // c0 folded here
            }
        } else {
            #pragma unroll
            for (int r = 0; r < 16; ++r) {
                const int row = (r & 3) + 8 * (r >> 2) + 4 * g;
                P1[(mt1 * 32 + row) * PST + n31] = acc[r];
            }
        }
    }
    __syncthreads();

    // ---- Phase 2 (fused): softmax + direct attn-fragment scatter ----
    if (tid < 256) {
        const int h = tid >> 5;          // 0..7
        const int p = tid & 31;
        float v[R_];
        float mx = -1e30f;
        #pragma unroll
        for (int r = 0; r < R_; ++r) {
            const int row = r * NH_ + h;
            v[r] = P0[row * PST + p] + P1[row * PST + p];
            mx = fmaxf(mx, v[r]);
        }
        float s = 0.f;
        #pragma unroll
        for (int r = 0; r < R_; ++r) { v[r] = __expf(v[r] - mx); s += v[r]; }
        const float inv = 1.f / s;

        short* bfs = reinterpret_cast<short*>(Bf);
        #pragma unroll
        for (int r = 0; r < R_; ++r) {
            const float a  = v[r] * inv;
            const short hi = bf16rn(a);
            const short lo = bf16rn(a - bf16tof(hi));
            const int kt   = r >> 1;
            const int lane = (r & 1) * 32 + p;
            bfs[((kt * 2 + 0) * 64 + lane) * 8 + h] = hi;
            bfs[((kt * 2 + 1) * 64 + lane) * 8 + h] = lo;
        }
    }

    // prefetch first GEMM2 A-frag pair (global only; overlaps softmax)
    const short8 u0h = *reinterpret_cast<const short8*>(
        Uf_hi + ((size_t)w * 64 + l) * 8);             // kt=0 -> idx = mt = w
    const short8 u0l = *reinterpret_cast<const short8*>(
        Uf_lo + ((size_t)w * 64 + l) * 8);
    __syncthreads();

    // ---- Phase 3: GEMM2 (M=256 c, N=32, K=128) + store ----
    {
        const int mt = w;                // c tile [32w, 32w+32)
        f32x16 p, q;
        #pragma unroll
        for (int i = 0; i < 16; ++i) { p[i] = 0.f; q[i] = 0.f; }

        // peeled kt=0
        {
            const short8 bhi = Bf[0 * 64 + l];
            const short8 blo = Bf[1 * 64 + l];
            p = __builtin_amdgcn_mfma_f32_32x32x16_bf16(u0h, bhi, p, 0, 0, 0);
            q = __builtin_amdgcn_mfma_f32_32x32x16_bf16(u0h, blo, q, 0, 0, 0);
            q = __builtin_amdgcn_mfma_f32_32x32x16_bf16(u0l, bhi, q, 0, 0, 0);
        }
        #pragma unroll 2
        for (int kt = 1; kt < 8; ++kt) {
            const short8 bhi = Bf[(kt * 2 + 0) * 64 + l];
            const short8 blo = Bf[(kt * 2 + 1) * 64 + l];
            const short8 ahi = *reinterpret_cast<const short8*>(
                Uf_hi + ((size_t)(kt * 8 + mt) * 64 + l) * 8);
            const short8 alo = *reinterpret_cast<const short8*>(
                Uf_lo + ((size_t)(kt * 8 + mt) * 64 + l) * 8);
            p = __builtin_amdgcn_mfma_f32_32x32x16_bf16(ahi, bhi, p, 0, 0, 0);
            q = __builtin_amdgcn_mfma_f32_32x32x16_bf16(ahi, blo, q, 0, 0, 0);
            q = __builtin_amdgcn_mfma_f32_32x32x16_bf16(alo, bhi, q, 0, 0, 0);
        }
        const f32x16 o = p + q;

        float* ob = out + (size_t)b * C_ * XY_ + xy0 + n31;
        #pragma unroll
        for (int r = 0; r < 16; ++r) {
            const int row = (r & 3) + 8 * (r >> 2) + 4 * g;
            ob[(size_t)(mt * 32 + row) * XY_] = o[r];
        }
    }
}

// ---------------------------------------------------------------------------
extern "C" void kernel_launch(void* const* d_in, const int* in_sizes, int n_in,
                              void* d_out, int out_size, void* d_ws, size_t ws_size,
                              hipStream_t stream)
{
    const float* z    = (const float*)d_in[0];
    const float* rims = (const float*)d_in[1];
    const float* Wk   = (const float*)d_in[2];
    const float* bk   = (const float*)d_in[3];
    const float* Wv   = (const float*)d_in[4];
    const float* bv   = (const float*)d_in[5];
    const float* Wq   = (const float*)d_in[6];
    const float* bq   = (const float*)d_in[7];
    const float* Wm   = (const float*)d_in[8];
    const float* bm   = (const float*)d_in[9];
    float* out = (float*)d_out;

    // ws: WLf_hi/lo (32768 shorts each) | Uf_hi/lo | c0 (256 f)
    short* WLf_hi = (short*)d_ws;
    short* WLf_lo = WLf_hi + 32768;
    short* Uf_hi  = WLf_lo + 32768;
    short* Uf_lo  = Uf_hi + 32768;
    float* c0o    = (float*)(Uf_lo + 32768);

    rims_precompute<<<2 * RH_, 512, 0, stream>>>(rims, Wk, bk, Wv, bv, Wq, bq,
                                                 Wm, bm, WLf_hi, WLf_lo,
                                                 Uf_hi, Uf_lo, c0o);
    rims_mfma<<<(B_ * XY_) / NT, 512, 0, stream>>>(z, WLf_hi, WLf_lo,
                                                   Uf_hi, Uf_lo, c0o, out);
}